// Round 7
// baseline (465.547 us; speedup 1.0000x reference)
//
#include <hip/hip_runtime.h>
#include <stdint.h>

// ---------------- problem constants ----------------
#define K_TOTAL   98304u     // 32 * 512 * 6
#define EMA_RATE  0.003f

// ---------------- select config ----------------
#define SBINS      4096      // sample hist bins (top 12 bits of key)
#define SSHIFT     20
#define S_THREADS  1024
#define S_V4       8192      // 8192 float4 = 32768 floats, 8 per thread
#define STARGET    320u      // ~2.5x K fraction; one margin bin added below

#define CBINS      4096      // candidate hist bins
#define CSHIFT     12        // bin width = 4096 keys
#define CAP2       16384u    // bin-g* candidate cap
#define OCAP       65536u    // overflow spill cap
#define EQCAP      256       // tie buffer

#define MP_BLOCKS  3072
#define MP_THREADS 256
#define MP_U       8         // 3072*256*8 = 6291456 float4 = nvec exactly
#define NWAVES     (MP_BLOCKS * MP_THREADS / 64)   // 12288
#define WCAP       128       // per-wave slots (mean ~50, +10 sigma safe)

// ctrs: [0]=ocnt [1]=cnt2 [2]=base [3]=gstar [4]=need2 [5]=done_main [6]=done_sf

// monotone float->uint key: order(key) == order(float)
__device__ __forceinline__ unsigned f2key(float x) {
    unsigned u = __float_as_uint(x);
    return (u & 0x80000000u) ? ~u : (u | 0x80000000u);
}
__device__ __forceinline__ float key2f(unsigned key) {
    unsigned u = (key & 0x80000000u) ? (key & 0x7FFFFFFFu) : ~key;
    return __uint_as_float(u);
}
__device__ __forceinline__ unsigned aload(const unsigned* p) {
    return __hip_atomic_load(p, __ATOMIC_RELAXED, __HIP_MEMORY_SCOPE_AGENT);
}

// ---------------- S: single-block sample + scan + zero-init ----------------
__global__ __launch_bounds__(S_THREADS) void sample_kernel(
        const float4* __restrict__ in, unsigned* __restrict__ ctrs,
        unsigned* __restrict__ ghist) {
    __shared__ unsigned h[SBINS];
    __shared__ unsigned psum[S_THREADS];
    int t = threadIdx.x;
    for (int i = t; i < SBINS; i += S_THREADS) h[i] = 0;
    for (int i = t; i < CBINS; i += S_THREADS) ghist[i] = 0;   // init for main
    if (t < 16) ctrs[t] = 0;
    __syncthreads();

    float4 v[8];
    #pragma unroll
    for (int u = 0; u < 8; ++u) v[u] = in[t + u * S_THREADS];  // 8 loads MLP
    #pragma unroll
    for (int u = 0; u < 8; ++u) {
        atomicAdd(&h[f2key(v[u].x) >> SSHIFT], 1u);
        atomicAdd(&h[f2key(v[u].y) >> SSHIFT], 1u);
        atomicAdd(&h[f2key(v[u].z) >> SSHIFT], 1u);
        atomicAdd(&h[f2key(v[u].w) >> SSHIFT], 1u);
    }
    __syncthreads();

    const int GB = SBINS / S_THREADS;         // 4 bins/thread, descending
    int hi = SBINS - 1 - t * GB;
    unsigned c[GB];
    #pragma unroll
    for (int j = 0; j < GB; ++j) c[j] = h[hi - j];
    unsigned s = 0;
    #pragma unroll
    for (int j = 0; j < GB; ++j) s += c[j];
    psum[t] = s;
    __syncthreads();
    for (int off = 1; off < S_THREADS; off <<= 1) {
        unsigned o = (t >= off) ? psum[t - off] : 0u;
        __syncthreads();
        psum[t] += o;
        __syncthreads();
    }
    unsigned cum = psum[t] - s;               // samples strictly above my group
    for (int j = 0; j < GB; ++j) {
        if (cum < STARGET && cum + c[j] >= STARGET) {
            unsigned bin = (unsigned)(hi - j);
            unsigned bb = (bin > 0) ? bin - 1 : 0;   // one margin bin
            ctrs[2] = bb << SSHIFT;                  // base key
        }
        cum += c[j];
    }
}

// ---------------- P: one-shot stream + compact + LDS hist + lastblock scan -
__global__ __launch_bounds__(MP_THREADS) void main_pass_kernel(
        const float4* __restrict__ in, unsigned* __restrict__ ctrs,
        uint2* __restrict__ wreg, unsigned* __restrict__ wcnt,
        uint2* __restrict__ ovf, unsigned* __restrict__ ghist) {
    __shared__ unsigned h[CBINS];
    __shared__ unsigned psum[MP_THREADS];
    __shared__ unsigned sh_last;
    const unsigned t = threadIdx.x;
    for (int i = t; i < CBINS; i += MP_THREADS) h[i] = 0;
    const unsigned gtid = blockIdx.x * MP_THREADS + t;
    const unsigned nth  = MP_BLOCKS * MP_THREADS;
    unsigned base = ctrs[2];
    float thresh = key2f(base);
    __syncthreads();

    float4 v[MP_U];
    #pragma unroll
    for (int u = 0; u < MP_U; ++u) v[u] = in[gtid + u * nth];  // 8 loads MLP
    __builtin_amdgcn_sched_barrier(0);        // keep loads above branchy code

    unsigned gw = gtid >> 6;
    uint2* wb = wreg + (size_t)gw * WCAP;
    unsigned wcount = 0;
    #pragma unroll
    for (int u = 0; u < MP_U; ++u) {
        float xs[4] = {v[u].x, v[u].y, v[u].z, v[u].w};
        #pragma unroll
        for (int c = 0; c < 4; ++c) {
            bool pred = xs[c] >= thresh;      // == key>=base: thresh>0, no NaN
            unsigned long long mask = __ballot(pred);
            if (mask) {                        // wave-uniform
                if (pred) {                    // ~2% of elements
                    unsigned key = f2key(xs[c]);
                    unsigned g = (key - base) >> CSHIFT;
                    if (g > CBINS - 1) g = CBINS - 1;
                    atomicAdd(&h[g], 1u);
                    unsigned prefix = __builtin_amdgcn_mbcnt_hi(
                        (unsigned)(mask >> 32),
                        __builtin_amdgcn_mbcnt_lo((unsigned)mask, 0u));
                    unsigned off = wcount + prefix;
                    unsigned idx = 4u * (gtid + u * nth) + c;
                    if (off < WCAP) {
                        wb[off] = make_uint2(key, idx);
                    } else {                   // never-taken safety spill
                        unsigned q = atomicAdd(&ctrs[0], 1u);
                        if (q < OCAP) ovf[q] = make_uint2(key, idx);
                    }
                }
                wcount += (unsigned)__popcll(mask);
            }
        }
    }
    if ((t & 63u) == 0) wcnt[gw] = (wcount < WCAP) ? wcount : WCAP;
    __syncthreads();
    for (int i = t; i < CBINS; i += MP_THREADS) {
        unsigned c = h[i];
        if (c) atomicAdd(&ghist[i], c);       // sparse merge
    }
    __syncthreads();

    // ---- last block scans ghist -> g*, need2 (device-scope handshake) ----
    if (t == 0) {
        __threadfence();
        unsigned prev = __hip_atomic_fetch_add(&ctrs[5], 1u,
                            __ATOMIC_ACQ_REL, __HIP_MEMORY_SCOPE_AGENT);
        sh_last = (prev == gridDim.x - 1) ? 1u : 0u;
    }
    __syncthreads();
    if (!sh_last) return;
    __threadfence();

    const int GB = CBINS / MP_THREADS;        // 16 bins/thread, descending
    int hi = CBINS - 1 - t * GB;
    unsigned c[GB];
    #pragma unroll
    for (int j = 0; j < GB; ++j) c[j] = aload(&ghist[hi - j]);
    unsigned s = 0;
    #pragma unroll
    for (int j = 0; j < GB; ++j) s += c[j];
    psum[t] = s;
    __syncthreads();
    for (int off = 1; off < MP_THREADS; off <<= 1) {
        unsigned o = (t >= off) ? psum[t - off] : 0u;
        __syncthreads();
        psum[t] += o;
        __syncthreads();
    }
    unsigned cum = psum[t] - s;
    for (int j = 0; j < GB; ++j) {
        if (cum < K_TOTAL && cum + c[j] >= K_TOTAL) {
            ctrs[3] = (unsigned)(hi - j);     // g*
            ctrs[4] = K_TOTAL - cum;          // need2 inside bin g*
        }
        cum += c[j];
    }
}

// ---------------- SF: scatter winners + (last block) exact select ----------
#define SF_BLOCKS 256
__global__ __launch_bounds__(256) void scatter_final_kernel(
        const uint2* __restrict__ wreg, const unsigned* __restrict__ wcnt,
        const uint2* __restrict__ ovf, unsigned* __restrict__ ctrs,
        unsigned long long* __restrict__ kc2, float* __restrict__ out,
        const float* __restrict__ thr_in, float* __restrict__ thr_out) {
    __shared__ unsigned h[CBINS];             // reused: exact-key hist
    __shared__ unsigned psum[256];
    __shared__ unsigned eqidx[EQCAP];
    __shared__ unsigned eqcnt;
    __shared__ unsigned sh_low, sh_need3, sh_last;
    const unsigned t = threadIdx.x;
    unsigned base  = ctrs[2];
    unsigned gstar = ctrs[3];
    unsigned tid = blockIdx.x * 256 + t;
    unsigned nth = SF_BLOCKS * 256;
    const unsigned NSLOT = NWAVES * WCAP;

    for (unsigned s = tid; s < NSLOT; s += nth) {
        unsigned w = s >> 7;                   // WCAP == 128
        if ((s & 127u) < wcnt[w]) {
            uint2 e = wreg[s];
            unsigned g = (e.x - base) >> CSHIFT;
            if (g > CBINS - 1) g = CBINS - 1;
            if (g > gstar) {
                out[e.y] = fmaxf(key2f(e.x), 0.0f);      // definite winner
            } else if (g == gstar) {
                unsigned p = atomicAdd(&ctrs[1], 1u);
                if (p < CAP2) {
                    unsigned long long pk =
                        ((unsigned long long)e.y << 32) | e.x;
                    __hip_atomic_store(&kc2[p], pk, __ATOMIC_RELAXED,
                                       __HIP_MEMORY_SCOPE_AGENT);
                }
            }
        }
    }
    unsigned no = min(aload(&ctrs[0]), (unsigned)OCAP);  // expected 0
    for (unsigned s = tid; s < no; s += nth) {
        uint2 e = ovf[s];
        unsigned g = (e.x - base) >> CSHIFT;
        if (g > CBINS - 1) g = CBINS - 1;
        if (g > gstar) {
            out[e.y] = fmaxf(key2f(e.x), 0.0f);
        } else if (g == gstar) {
            unsigned p = atomicAdd(&ctrs[1], 1u);
            if (p < CAP2) {
                unsigned long long pk = ((unsigned long long)e.y << 32) | e.x;
                __hip_atomic_store(&kc2[p], pk, __ATOMIC_RELAXED,
                                   __HIP_MEMORY_SCOPE_AGENT);
            }
        }
    }
    __syncthreads();

    // ---- last block performs the exact selection ----
    if (t == 0) {
        __threadfence();
        unsigned prev = __hip_atomic_fetch_add(&ctrs[6], 1u,
                            __ATOMIC_ACQ_REL, __HIP_MEMORY_SCOPE_AGENT);
        sh_last = (prev == gridDim.x - 1) ? 1u : 0u;
    }
    __syncthreads();
    if (!sh_last) return;
    __threadfence();

    unsigned nc2   = min(aload(&ctrs[1]), (unsigned)CAP2);
    unsigned base3 = base + (gstar << CSHIFT);
    unsigned need2 = ctrs[4];
    const int NB = 1 << CSHIFT;               // 4096 exact keys

    for (int i = t; i < NB; i += 256) h[i] = 0;
    if (t == 0) eqcnt = 0;
    __syncthreads();
    for (unsigned i = t; i < nc2; i += 256) {
        unsigned long long pk = __hip_atomic_load(&kc2[i], __ATOMIC_RELAXED,
                                                  __HIP_MEMORY_SCOPE_AGENT);
        unsigned low = (unsigned)pk - base3;
        if (low > (unsigned)(NB - 1)) low = NB - 1;
        atomicAdd(&h[low], 1u);
    }
    __syncthreads();

    const int GB = NB / 256;                  // 16 keys/thread, descending
    int hi = NB - 1 - t * GB;
    unsigned s = 0;
    for (int j = 0; j < GB; ++j) s += h[hi - j];
    psum[t] = s;
    __syncthreads();
    for (int off = 1; off < 256; off <<= 1) {
        unsigned o = (t >= off) ? psum[t - off] : 0u;
        __syncthreads();
        psum[t] += o;
        __syncthreads();
    }
    unsigned cum = psum[t] - s;
    for (int j = 0; j < GB; ++j) {
        unsigned c = h[hi - j];
        if (cum < need2 && cum + c >= need2) {
            sh_low = (unsigned)(hi - j);
            sh_need3 = need2 - cum;           // ties accepted at kth key
        }
        cum += c;
    }
    __syncthreads();
    unsigned kth_key = base3 + sh_low;
    unsigned need3   = sh_need3;

    for (unsigned i = t; i < nc2; i += 256) {
        unsigned long long pk = __hip_atomic_load(&kc2[i], __ATOMIC_RELAXED,
                                                  __HIP_MEMORY_SCOPE_AGENT);
        unsigned key = (unsigned)pk;
        unsigned idx = (unsigned)(pk >> 32);
        if (key > kth_key) {
            out[idx] = fmaxf(key2f(key), 0.0f);
        } else if (key == kth_key) {
            unsigned p = atomicAdd(&eqcnt, 1u);
            if (p < EQCAP) eqidx[p] = idx;
        }
    }
    __syncthreads();

    // tie-break: lax.top_k picks lowest flat indices first
    unsigned ne = min(eqcnt, (unsigned)EQCAP);
    float vv = key2f(kth_key);
    for (unsigned e = t; e < ne; e += 256) {
        unsigned my = eqidx[e];
        unsigned rank = 0;
        for (unsigned f = 0; f < ne; ++f) rank += (eqidx[f] < my) ? 1u : 0u;
        if (rank < need3) out[my] = fmaxf(vv, 0.0f);
    }

    if (t == 0) {
        float mink = fmaxf(vv, 0.0f);         // relu(k-th largest)
        thr_out[0] = (1.0f - EMA_RATE) * thr_in[0] + EMA_RATE * mink;
    }
}

// ---------------- launch ----------------
extern "C" void kernel_launch(void* const* d_in, const int* in_sizes, int n_in,
                              void* d_out, int out_size, void* d_ws, size_t ws_size,
                              hipStream_t stream) {
    const float4* feat   = (const float4*)d_in[0];
    const float*  thr_in = (const float*)d_in[1];
    float* out = (float*)d_out;
    int N = in_sizes[0];         // 25165824

    // ---- workspace layout ----
    uint8_t* w = (uint8_t*)d_ws;
    unsigned*           ghist = (unsigned*)w;                      // 16 KB
    unsigned*           ctrs  = (unsigned*)(w + (16 << 10));       // 64 B
    unsigned*           wcnt  = (unsigned*)(w + (20 << 10));       // 48 KB
    uint2*              wreg  = (uint2*)(w + ((size_t)1 << 20));   // 12 MB
    uint2*              ovf   = (uint2*)(w + ((size_t)14 << 20));  // 512 KB
    unsigned long long* kc2   = (unsigned long long*)(w + ((size_t)15 << 20));

    hipMemsetAsync(d_out, 0, (size_t)N * 4, stream);   // fills run ~6.5 TB/s

    sample_kernel       <<<1, S_THREADS, 0, stream>>>(feat, ctrs, ghist);
    main_pass_kernel    <<<MP_BLOCKS, MP_THREADS, 0, stream>>>(
        feat, ctrs, wreg, wcnt, ovf, ghist);
    scatter_final_kernel<<<SF_BLOCKS, 256, 0, stream>>>(
        wreg, wcnt, ovf, ctrs, kc2, out, thr_in, out + N);
}

// Round 8
// 253.985 us; speedup vs baseline: 1.8330x; 1.8330x over previous
//
#include <hip/hip_runtime.h>
#include <stdint.h>

// ---------------- problem constants ----------------
#define K_TOTAL   98304u     // 32 * 512 * 6
#define EMA_RATE  0.003f

// ---------------- select config ----------------
#define SBINS      4096      // sample hist bins (top 12 bits of key)
#define SSHIFT     20
#define S_THREADS  1024
#define STARGET    320u      // ~1% of 32768 samples; margin bin added below

#define CBINS      4096      // candidate hist bins
#define CSHIFT     12        // bin width = 4096 keys
#define CAP2       16384u    // bin-g* candidate cap
#define OCAP       65536u    // overflow spill cap
#define EQCAP      256       // tie buffer
#define KCAP       (1u<<20)  // compact candidate list cap (mean ~450K)
#define LCAP       2048      // per-block LDS staging in gather

// mask pass geometry: 2048*256 threads, 12 iters, exact cover of nvec
#define MK_BLOCKS  2048
#define MK_THREADS 256
#define MK_NTH     (MK_BLOCKS * MK_THREADS)        // 524288
#define MK_NW      (MK_NTH / 64)                   // 8192 waves
#define MK_ITERS   12                              // 524288*12 = 6291456 = nvec
#define NSLOTS     (MK_NW * MK_ITERS)              // 98304 mask slots

#define GA_BLOCKS  384                             // 384*256 = NSLOTS
#define SF_BLOCKS  128

// ctrs: [0]=ovf cnt [1]=kcand cnt [2]=base [3]=gstar [4]=need2
//       [5]=done_gather [6]=done_sf [7]=cnt2(bin-g* list)

// monotone float->uint key: order(key) == order(float)
__device__ __forceinline__ unsigned f2key(float x) {
    unsigned u = __float_as_uint(x);
    return (u & 0x80000000u) ? ~u : (u | 0x80000000u);
}
__device__ __forceinline__ float key2f(unsigned key) {
    unsigned u = (key & 0x80000000u) ? (key & 0x7FFFFFFFu) : ~key;
    return __uint_as_float(u);
}
__device__ __forceinline__ unsigned aload(const unsigned* p) {
    return __hip_atomic_load(p, __ATOMIC_RELAXED, __HIP_MEMORY_SCOPE_AGENT);
}

// ---------------- S: single-block sample + scan + zero-init ----------------
__global__ __launch_bounds__(S_THREADS) void sample_kernel(
        const float4* __restrict__ in, unsigned* __restrict__ ctrs,
        unsigned* __restrict__ ghist) {
    __shared__ unsigned h[SBINS];
    __shared__ unsigned psum[S_THREADS];
    int t = threadIdx.x;
    for (int i = t; i < SBINS; i += S_THREADS) h[i] = 0;
    for (int i = t; i < CBINS; i += S_THREADS) ghist[i] = 0;
    if (t < 16) ctrs[t] = 0;
    __syncthreads();

    float4 v[8];
    #pragma unroll
    for (int u = 0; u < 8; ++u) v[u] = in[t + u * S_THREADS];  // 32K floats
    #pragma unroll
    for (int u = 0; u < 8; ++u) {
        atomicAdd(&h[f2key(v[u].x) >> SSHIFT], 1u);
        atomicAdd(&h[f2key(v[u].y) >> SSHIFT], 1u);
        atomicAdd(&h[f2key(v[u].z) >> SSHIFT], 1u);
        atomicAdd(&h[f2key(v[u].w) >> SSHIFT], 1u);
    }
    __syncthreads();

    const int GB = SBINS / S_THREADS;         // 4 bins/thread, descending
    int hi = SBINS - 1 - t * GB;
    unsigned c[GB];
    #pragma unroll
    for (int j = 0; j < GB; ++j) c[j] = h[hi - j];
    unsigned s = 0;
    #pragma unroll
    for (int j = 0; j < GB; ++j) s += c[j];
    psum[t] = s;
    __syncthreads();
    for (int off = 1; off < S_THREADS; off <<= 1) {
        unsigned o = (t >= off) ? psum[t - off] : 0u;
        __syncthreads();
        psum[t] += o;
        __syncthreads();
    }
    unsigned cum = psum[t] - s;               // samples strictly above my group
    for (int j = 0; j < GB; ++j) {
        if (cum < STARGET && cum + c[j] >= STARGET) {
            unsigned bin = (unsigned)(hi - j);
            unsigned bb = (bin > 0) ? bin - 1 : 0;   // one margin bin
            ctrs[2] = bb << SSHIFT;                  // base key
        }
        cum += c[j];
    }
}

// ---------------- M: branchless full-data mask pass ------------------------
__global__ __launch_bounds__(MK_THREADS, 4) void mask_kernel(
        const float4* __restrict__ in, const unsigned* __restrict__ ctrs,
        ulonglong4* __restrict__ maskbuf) {
    const float thresh = key2f(ctrs[2]);      // >0; x>=thresh <=> key>=base
    const unsigned gtid = blockIdx.x * MK_THREADS + threadIdx.x;
    const unsigned gw   = gtid >> 6;
    const unsigned lane = threadIdx.x & 63u;
    #pragma unroll
    for (int u = 0; u < MK_ITERS; ++u) {
        float4 v = in[gtid + u * MK_NTH];
        unsigned long long m0 = __ballot(v.x >= thresh);
        unsigned long long m1 = __ballot(v.y >= thresh);
        unsigned long long m2 = __ballot(v.z >= thresh);
        unsigned long long m3 = __ballot(v.w >= thresh);
        if (lane == 0)
            maskbuf[gw + u * MK_NW] = make_ulonglong4(m0, m1, m2, m3);
    }
}

// ---------------- G: gather candidates from bitmap + hist + g* scan --------
__global__ __launch_bounds__(256, 4) void gather_kernel(
        const float* __restrict__ inf, const ulonglong4* __restrict__ maskbuf,
        unsigned* __restrict__ ctrs, uint2* __restrict__ kcand,
        uint2* __restrict__ ovf, unsigned* __restrict__ ghist) {
    __shared__ unsigned h[CBINS];             // 16 KB
    __shared__ uint2    lbuf[LCAP];           // 16 KB
    __shared__ unsigned lcnt, lbase, sh_last;
    __shared__ unsigned psum[256];
    const unsigned t = threadIdx.x;
    for (int i = t; i < CBINS; i += 256) h[i] = 0;
    if (t == 0) lcnt = 0;
    unsigned base = ctrs[2];
    __syncthreads();

    const unsigned slot = blockIdx.x * 256 + t;      // one slot per thread
    ulonglong4 mw = maskbuf[slot];
    // invert mask layout: float4 base for this slot
    const unsigned i0 = 64u * (slot & (MK_NW - 1)) + (slot >> 13) * MK_NTH;
    unsigned long long ms[4] = {mw.x, mw.y, mw.z, mw.w};
    #pragma unroll
    for (int c = 0; c < 4; ++c) {
        unsigned long long m = ms[c];
        while (m) {
            unsigned l = (unsigned)__ffsll((long long)m) - 1u;
            m &= m - 1;
            unsigned ei = 4u * (i0 + l) + (unsigned)c;   // element index
            float x = inf[ei];                           // 4B gather (L3-hit)
            unsigned key = f2key(x);
            unsigned g = (key - base) >> CSHIFT;
            if (g > CBINS - 1) g = CBINS - 1;
            atomicAdd(&h[g], 1u);
            unsigned p = atomicAdd(&lcnt, 1u);
            if (p < LCAP) lbuf[p] = make_uint2(key, ei);
            else {                                       // safety spill
                unsigned q = atomicAdd(&ctrs[0], 1u);
                if (q < OCAP) ovf[q] = make_uint2(key, ei);
            }
        }
    }
    __syncthreads();
    unsigned n = min(lcnt, (unsigned)LCAP);
    if (t == 0) lbase = atomicAdd(&ctrs[1], n);
    __syncthreads();
    for (unsigned j = t; j < n; j += 256) {
        unsigned p = lbase + j;
        if (p < KCAP) kcand[p] = lbuf[j];
    }
    for (int i = t; i < CBINS; i += 256) {
        unsigned c = h[i];
        if (c) atomicAdd(&ghist[i], c);       // sparse merge
    }
    __syncthreads();

    // ---- last block scans ghist -> g*, need2 ----
    if (t == 0) {
        __threadfence();
        unsigned prev = __hip_atomic_fetch_add(&ctrs[5], 1u,
                            __ATOMIC_ACQ_REL, __HIP_MEMORY_SCOPE_AGENT);
        sh_last = (prev == gridDim.x - 1) ? 1u : 0u;
    }
    __syncthreads();
    if (!sh_last) return;
    __threadfence();

    const int GB = CBINS / 256;               // 16 bins/thread, descending
    int hi = CBINS - 1 - t * GB;
    unsigned c[GB];
    #pragma unroll
    for (int j = 0; j < GB; ++j) c[j] = aload(&ghist[hi - j]);
    unsigned s = 0;
    #pragma unroll
    for (int j = 0; j < GB; ++j) s += c[j];
    psum[t] = s;
    __syncthreads();
    for (int off = 1; off < 256; off <<= 1) {
        unsigned o = (t >= off) ? psum[t - off] : 0u;
        __syncthreads();
        psum[t] += o;
        __syncthreads();
    }
    unsigned cum = psum[t] - s;
    for (int j = 0; j < GB; ++j) {
        if (cum < K_TOTAL && cum + c[j] >= K_TOTAL) {
            ctrs[3] = (unsigned)(hi - j);     // g*
            ctrs[4] = K_TOTAL - cum;          // need2 inside bin g*
        }
        cum += c[j];
    }
}

// ---------------- SF: scatter winners + (last block) exact select ----------
__global__ __launch_bounds__(256) void scatter_final_kernel(
        const uint2* __restrict__ kcand, const uint2* __restrict__ ovf,
        unsigned* __restrict__ ctrs, unsigned long long* __restrict__ kc2,
        float* __restrict__ out,
        const float* __restrict__ thr_in, float* __restrict__ thr_out) {
    __shared__ unsigned h[CBINS];             // reused: exact-key hist
    __shared__ unsigned psum[256];
    __shared__ unsigned eqidx[EQCAP];
    __shared__ unsigned eqcnt;
    __shared__ unsigned sh_low, sh_need3, sh_last;
    const unsigned t = threadIdx.x;
    unsigned base  = ctrs[2];
    unsigned gstar = ctrs[3];
    unsigned tid = blockIdx.x * 256 + t;
    unsigned nth = SF_BLOCKS * 256;

    unsigned nc = min(aload(&ctrs[1]), (unsigned)KCAP);
    for (unsigned s = tid; s < nc; s += nth) {
        uint2 e = kcand[s];
        unsigned g = (e.x - base) >> CSHIFT;
        if (g > CBINS - 1) g = CBINS - 1;
        if (g > gstar) {
            out[e.y] = fmaxf(key2f(e.x), 0.0f);          // definite winner
        } else if (g == gstar) {
            unsigned p = atomicAdd(&ctrs[7], 1u);
            if (p < CAP2) {
                unsigned long long pk = ((unsigned long long)e.y << 32) | e.x;
                __hip_atomic_store(&kc2[p], pk, __ATOMIC_RELAXED,
                                   __HIP_MEMORY_SCOPE_AGENT);
            }
        }
    }
    unsigned no = min(aload(&ctrs[0]), (unsigned)OCAP);  // expected 0
    for (unsigned s = tid; s < no; s += nth) {
        uint2 e = ovf[s];
        unsigned g = (e.x - base) >> CSHIFT;
        if (g > CBINS - 1) g = CBINS - 1;
        if (g > gstar) {
            out[e.y] = fmaxf(key2f(e.x), 0.0f);
        } else if (g == gstar) {
            unsigned p = atomicAdd(&ctrs[7], 1u);
            if (p < CAP2) {
                unsigned long long pk = ((unsigned long long)e.y << 32) | e.x;
                __hip_atomic_store(&kc2[p], pk, __ATOMIC_RELAXED,
                                   __HIP_MEMORY_SCOPE_AGENT);
            }
        }
    }
    __syncthreads();

    // ---- last block performs the exact selection ----
    if (t == 0) {
        __threadfence();
        unsigned prev = __hip_atomic_fetch_add(&ctrs[6], 1u,
                            __ATOMIC_ACQ_REL, __HIP_MEMORY_SCOPE_AGENT);
        sh_last = (prev == gridDim.x - 1) ? 1u : 0u;
    }
    __syncthreads();
    if (!sh_last) return;
    __threadfence();

    unsigned nc2   = min(aload(&ctrs[7]), (unsigned)CAP2);
    unsigned base3 = base + (gstar << CSHIFT);
    unsigned need2 = ctrs[4];
    const int NB = 1 << CSHIFT;               // 4096 exact keys

    for (int i = t; i < NB; i += 256) h[i] = 0;
    if (t == 0) eqcnt = 0;
    __syncthreads();
    for (unsigned i = t; i < nc2; i += 256) {
        unsigned long long pk = __hip_atomic_load(&kc2[i], __ATOMIC_RELAXED,
                                                  __HIP_MEMORY_SCOPE_AGENT);
        unsigned low = (unsigned)pk - base3;
        if (low > (unsigned)(NB - 1)) low = NB - 1;
        atomicAdd(&h[low], 1u);
    }
    __syncthreads();

    const int GB = NB / 256;                  // 16 keys/thread, descending
    int hi = NB - 1 - t * GB;
    unsigned s = 0;
    for (int j = 0; j < GB; ++j) s += h[hi - j];
    psum[t] = s;
    __syncthreads();
    for (int off = 1; off < 256; off <<= 1) {
        unsigned o = (t >= off) ? psum[t - off] : 0u;
        __syncthreads();
        psum[t] += o;
        __syncthreads();
    }
    unsigned cum = psum[t] - s;
    for (int j = 0; j < GB; ++j) {
        unsigned c = h[hi - j];
        if (cum < need2 && cum + c >= need2) {
            sh_low = (unsigned)(hi - j);
            sh_need3 = need2 - cum;           // ties accepted at kth key
        }
        cum += c;
    }
    __syncthreads();
    unsigned kth_key = base3 + sh_low;
    unsigned need3   = sh_need3;

    for (unsigned i = t; i < nc2; i += 256) {
        unsigned long long pk = __hip_atomic_load(&kc2[i], __ATOMIC_RELAXED,
                                                  __HIP_MEMORY_SCOPE_AGENT);
        unsigned key = (unsigned)pk;
        unsigned idx = (unsigned)(pk >> 32);
        if (key > kth_key) {
            out[idx] = fmaxf(key2f(key), 0.0f);
        } else if (key == kth_key) {
            unsigned p = atomicAdd(&eqcnt, 1u);
            if (p < EQCAP) eqidx[p] = idx;
        }
    }
    __syncthreads();

    // tie-break: lax.top_k picks lowest flat indices first
    unsigned ne = min(eqcnt, (unsigned)EQCAP);
    float vv = key2f(kth_key);
    for (unsigned e = t; e < ne; e += 256) {
        unsigned my = eqidx[e];
        unsigned rank = 0;
        for (unsigned f = 0; f < ne; ++f) rank += (eqidx[f] < my) ? 1u : 0u;
        if (rank < need3) out[my] = fmaxf(vv, 0.0f);
    }

    if (t == 0) {
        float mink = fmaxf(vv, 0.0f);         // relu(k-th largest)
        thr_out[0] = (1.0f - EMA_RATE) * thr_in[0] + EMA_RATE * mink;
    }
}

// ---------------- launch ----------------
extern "C" void kernel_launch(void* const* d_in, const int* in_sizes, int n_in,
                              void* d_out, int out_size, void* d_ws, size_t ws_size,
                              hipStream_t stream) {
    const float4* feat   = (const float4*)d_in[0];
    const float*  featf  = (const float*)d_in[0];
    const float*  thr_in = (const float*)d_in[1];
    float* out = (float*)d_out;
    int N = in_sizes[0];         // 25165824

    // ---- workspace layout ----
    uint8_t* w = (uint8_t*)d_ws;
    unsigned*           ghist   = (unsigned*)w;                       // 16 KB
    unsigned*           ctrs    = (unsigned*)(w + (16 << 10));        // 64 B
    ulonglong4*         maskbuf = (ulonglong4*)(w + ((size_t)1 << 20));  // 3 MB
    uint2*              kcand   = (uint2*)(w + ((size_t)8 << 20));    // 8 MB
    uint2*              ovf     = (uint2*)(w + ((size_t)16 << 20));   // 512 KB
    unsigned long long* kc2     = (unsigned long long*)(w + ((size_t)17 << 20));

    hipMemsetAsync(d_out, 0, (size_t)N * 4, stream);   // fill runs ~6.5 TB/s

    sample_kernel       <<<1, S_THREADS, 0, stream>>>(feat, ctrs, ghist);
    mask_kernel         <<<MK_BLOCKS, MK_THREADS, 0, stream>>>(feat, ctrs, maskbuf);
    gather_kernel       <<<GA_BLOCKS, 256, 0, stream>>>(featf, maskbuf, ctrs,
                                                        kcand, ovf, ghist);
    scatter_final_kernel<<<SF_BLOCKS, 256, 0, stream>>>(kcand, ovf, ctrs, kc2,
                                                        out, thr_in, out + N);
}